// Round 6
// baseline (351.609 us; speedup 1.0000x reference)
//
#include <hip/hip_runtime.h>
#include <math.h>

#define NEG_SLOPE 0.2f
#define CAP 256     // max degree on the agg fast path
#define BSH 9       // node-bucket shift: 512 nodes/bucket
#define BSZ 512
#define CHUNK 8192  // edges per k_scatter block

__device__ __forceinline__ float hred_sum(float v) {   // 32-wide (half-wave) reduce
#pragma unroll
    for (int o = 16; o >= 1; o >>= 1) v += __shfl_xor(v, o, 64);
    return v;
}
// fp32 -> bf16 (RNE), and bf16(lo/hi of uint) -> fp32
__device__ __forceinline__ unsigned int f2bf(float f) {
    unsigned int u = __float_as_uint(f);
    return (u + 0x7fffu + ((u >> 16) & 1u)) >> 16;
}
__device__ __forceinline__ float bflo(unsigned int u) { return __uint_as_float(u << 16); }
__device__ __forceinline__ float bfhi(unsigned int u) { return __uint_as_float(u & 0xffff0000u); }

// ---------------- CSR build: bucketed counting sort ----------------

__global__ __launch_bounds__(256) void k_zero(int* p, int n) {
    int i = blockIdx.x * 256 + threadIdx.x;
    if (i < n) p[i] = 0;
}

__global__ __launch_bounds__(256) void k_hist(const int* __restrict__ dst, int* __restrict__ bcount, int E) {
    __shared__ int lh[256];
    lh[threadIdx.x] = 0;
    __syncthreads();
    int stride = gridDim.x * 256;
    for (int i = blockIdx.x * 256 + threadIdx.x; i < E; i += stride)
        atomicAdd(&lh[dst[i] >> BSH], 1);
    __syncthreads();
    int c = lh[threadIdx.x];
    if (c) atomicAdd(&bcount[threadIdx.x], c);
}

__global__ __launch_bounds__(256) void k_bscan(const int* __restrict__ bcount,
                                               int* __restrict__ eoff, int* __restrict__ boff,
                                               int* __restrict__ bcursor, int* __restrict__ rowptr,
                                               int nbuck, int N, int E) {
    __shared__ int s1[256], s2[256];
    int t = threadIdx.x;
    int bc = (t < nbuck) ? bcount[t] : 0;
    int cn = 0;
    if (t < nbuck) { cn = N - (t << BSH); if (cn > BSZ) cn = BSZ; if (cn < 0) cn = 0; }
    int tot = bc + cn;
    s1[t] = bc; s2[t] = tot;
    __syncthreads();
#pragma unroll
    for (int off = 1; off < 256; off <<= 1) {
        int u1 = (t >= off) ? s1[t - off] : 0;
        int u2 = (t >= off) ? s2[t - off] : 0;
        __syncthreads();
        s1[t] += u1; s2[t] += u2;
        __syncthreads();
    }
    if (t < nbuck) {
        int e = s1[t] - bc, b = s2[t] - tot;
        eoff[t] = e; boff[t] = b; bcursor[t] = e;
    }
    if (t == 0) rowptr[N] = E + N;
}

__global__ __launch_bounds__(256) void k_scatter(const int* __restrict__ src, const int* __restrict__ dst,
                                                 int* __restrict__ bcursor, int* __restrict__ ebuf, int E) {
    __shared__ int lh[256], lb[256];
    int base = blockIdx.x * CHUNK;
    int end = base + CHUNK; if (end > E) end = E;
    lh[threadIdx.x] = 0;
    __syncthreads();
    for (int i = base + threadIdx.x; i < end; i += 256)
        atomicAdd(&lh[dst[i] >> BSH], 1);
    __syncthreads();
    int c = lh[threadIdx.x];
    lb[threadIdx.x] = c ? atomicAdd(&bcursor[threadIdx.x], c) : 0;
    lh[threadIdx.x] = 0;
    __syncthreads();
    for (int i = base + threadIdx.x; i < end; i += 256) {
        int d = dst[i], b = d >> BSH;
        int p = atomicAdd(&lh[b], 1);
        ebuf[lb[b] + p] = (src[i] << BSH) | (d & (BSZ - 1));
    }
}

__global__ __launch_bounds__(512) void k_build(const int* __restrict__ eoff, const int* __restrict__ boff,
                                               const int* __restrict__ bcount, const int* __restrict__ ebuf,
                                               int* __restrict__ rowptr, int* __restrict__ csr, int N) {
    __shared__ int sdeg[BSZ], sscan[BSZ];
    int b = blockIdx.x, t = threadIdx.x;
    int nlo = b << BSH;
    int cn = N - nlo; if (cn > BSZ) cn = BSZ;
    int e0 = eoff[b], ec = bcount[b], cb = boff[b];
    sdeg[t] = (t < cn) ? 1 : 0;
    __syncthreads();
    for (int i = t; i < ec; i += 512)
        atomicAdd(&sdeg[ebuf[e0 + i] & (BSZ - 1)], 1);
    __syncthreads();
    int v = sdeg[t];
    sscan[t] = v;
    __syncthreads();
#pragma unroll
    for (int off = 1; off < BSZ; off <<= 1) {
        int u = (t >= off) ? sscan[t - off] : 0;
        __syncthreads();
        sscan[t] += u;
        __syncthreads();
    }
    int excl = sscan[t] - v;
    if (t < cn) {
        rowptr[nlo + t] = cb + excl;
        csr[cb + excl] = nlo + t;
        sdeg[t] = excl + 1;
    }
    __syncthreads();
    for (int i = t; i < ec; i += 512) {
        int rec = ebuf[e0 + i];
        int p = atomicAdd(&sdeg[rec & (BSZ - 1)], 1);
        csr[cb + p] = rec >> BSH;
    }
}

// ---------------- GEMM: H = X @ W (+bias), optional ss/sd, optional bf16 H ----
// block = 256 (4 waves), 128 rows/block, lane tile 4 rows x 8 cols.
// Per-chunk staging of BOTH X and W (25 KB LDS total -> 4-6 blocks/CU),
// register prefetch of chunk c+1 overlapping compute of chunk c,
// ping-pong LDS buffers, ONE barrier per chunk.

template <int K, int OUTW, bool SS, bool HB>
__global__ __launch_bounds__(256) void k_gemm(const float* __restrict__ X,
                                              const float* __restrict__ W,
                                              const float* __restrict__ a_s,
                                              const float* __restrict__ a_d,
                                              const float* __restrict__ bias,
                                              void* __restrict__ Hout,
                                              float* __restrict__ ss,
                                              float* __restrict__ sd, int N) {
    constexpr int CH  = 16;
    constexpr int XS  = 132;          // 128 rows + 4 pad
    constexpr int NCH = K / CH;
    __shared__ __align__(16) float ws[2][CH * 64];
    __shared__ __align__(16) float xs[2][CH * XS];

    const int tid  = threadIdx.x;
    const int lane = tid & 63;
    const int w    = tid >> 6;
    const int rg   = lane >> 3;
    const int og   = lane & 7;
    const int rowbase = blockIdx.x * 128;
    const int rr   = w * 32 + rg * 4;
    const int r0   = rowbase + rr;

    // fixed staging assignment: 2 float4 of X per thread per chunk
    const float* xptr[2];
    int xrow[2], xq[2];
#pragma unroll
    for (int it = 0; it < 2; ++it) {
        int idx = it * 256 + tid;          // 0..511
        int row = idx >> 2;                // 0..127
        int q   = idx & 3;                 // quad within chunk
        int grow = rowbase + row; grow = grow < N ? grow : N - 1;
        xrow[it] = row; xq[it] = q;
        xptr[it] = X + (size_t)grow * K + q * 4;
    }

    float4 xpre[2];
    float  wpre[4];

    auto loadW = [&](int kc) {
        if (OUTW == 64) {
            *(float4*)wpre = *(const float4*)&W[kc * 64 + tid * 4];
        } else {
#pragma unroll
            for (int u = 0; u < 4; ++u) {
                int i = tid * 4 + u;          // 0..1023
                int k = i >> 6, o = i & 63;
                wpre[u] = (o < OUTW) ? W[(kc + k) * OUTW + o] : 0.f;
            }
        }
    };
    auto storeChunk = [&](int buf) {
        *(float4*)&ws[buf][tid * 4] = *(float4*)wpre;
#pragma unroll
        for (int it = 0; it < 2; ++it) {
            float4 v = xpre[it];
            int b = xq[it] * 4 * XS + xrow[it];
            xs[buf][b + 0 * XS] = v.x;
            xs[buf][b + 1 * XS] = v.y;
            xs[buf][b + 2 * XS] = v.z;
            xs[buf][b + 3 * XS] = v.w;
        }
    };

    float acc[4][8];
#pragma unroll
    for (int i = 0; i < 4; ++i)
#pragma unroll
        for (int j = 0; j < 8; ++j) acc[i][j] = 0.f;

    // prologue: stage chunk 0
    xpre[0] = *(const float4*)(xptr[0]);
    xpre[1] = *(const float4*)(xptr[1]);
    loadW(0);
    storeChunk(0);
    __syncthreads();

    for (int c = 0; c < NCH; ++c) {
        const int cur = c & 1;
        // prefetch chunk c+1 into registers (latency hidden by compute below)
        if (c + 1 < NCH) {
            int kc = (c + 1) * CH;
            xpre[0] = *(const float4*)(xptr[0] + kc);
            xpre[1] = *(const float4*)(xptr[1] + kc);
            loadW(kc);
        }
#pragma unroll
        for (int k = 0; k < CH; ++k) {
            const float4 a  = *(const float4*)&xs[cur][k * XS + rr];
            const float4 b0 = *(const float4*)&ws[cur][k * 64 + og * 8];
            const float4 b1 = *(const float4*)&ws[cur][k * 64 + og * 8 + 4];
            const float av[4]  = {a.x, a.y, a.z, a.w};
            const float bv8[8] = {b0.x, b0.y, b0.z, b0.w, b1.x, b1.y, b1.z, b1.w};
#pragma unroll
            for (int i = 0; i < 4; ++i)
#pragma unroll
                for (int j = 0; j < 8; ++j)
                    acc[i][j] = fmaf(av[i], bv8[j], acc[i][j]);
        }
        if (c + 1 < NCH) {
            // safe: buffer cur^1 was last READ at chunk c-1; the barrier at the
            // end of chunk c-1 ordered those reads before these writes.
            storeChunk(cur ^ 1);
            __syncthreads();
        }
    }

    if (SS) {
        float asv[8], adv[8];
        *(float4*)&asv[0] = *(const float4*)&a_s[og * 8];
        *(float4*)&asv[4] = *(const float4*)&a_s[og * 8 + 4];
        *(float4*)&adv[0] = *(const float4*)&a_d[og * 8];
        *(float4*)&adv[4] = *(const float4*)&a_d[og * 8 + 4];
#pragma unroll
        for (int i = 0; i < 4; ++i) {
            float s = 0.f, d = 0.f;
#pragma unroll
            for (int j = 0; j < 8; ++j) {
                s = fmaf(acc[i][j], asv[j], s);
                d = fmaf(acc[i][j], adv[j], d);
            }
#pragma unroll
            for (int o = 1; o <= 4; o <<= 1) {
                s += __shfl_xor(s, o, 64);
                d += __shfl_xor(d, o, 64);
            }
            if (og == 0 && r0 + i < N) { ss[r0 + i] = s; sd[r0 + i] = d; }
        }
    }

#pragma unroll
    for (int i = 0; i < 4; ++i) {
        int r = r0 + i;
        if (r >= N) continue;
        if (HB) {
            unsigned int* hb = (unsigned int*)Hout;
            uint4 u;
            u.x = (f2bf(acc[i][1]) << 16) | f2bf(acc[i][0]);
            u.y = (f2bf(acc[i][3]) << 16) | f2bf(acc[i][2]);
            u.z = (f2bf(acc[i][5]) << 16) | f2bf(acc[i][4]);
            u.w = (f2bf(acc[i][7]) << 16) | f2bf(acc[i][6]);
            *(uint4*)&hb[(size_t)r * 32 + og * 4] = u;
        } else if (OUTW == 64) {
            float* H = (float*)Hout;
            float4 o0 = make_float4(acc[i][0], acc[i][1], acc[i][2], acc[i][3]);
            float4 o1 = make_float4(acc[i][4], acc[i][5], acc[i][6], acc[i][7]);
            *(float4*)&H[(size_t)r * 64 + og * 8]     = o0;
            *(float4*)&H[(size_t)r * 64 + og * 8 + 4] = o1;
        } else {
            float* H = (float*)Hout;
#pragma unroll
            for (int j = 0; j < 8; ++j) {
                int o = og * 8 + j;
                if (o < OUTW) H[(size_t)r * OUTW + o] = acc[i][j] + bias[o];
            }
        }
    }
}

// ---------------- Aggregation: z[n] = elu( sum_j alpha_j h[src_j] + b ) ------
// half-wave (32 lanes) per node, 8 nodes/block. Softmax without max-subtraction
// (scores bounded ~|10| << 88, shift-invariant). One fused score+exp+sum pass,
// then gather: lane p holds packed bf16 features 2p,2p+1 of the accumulator.

__global__ __launch_bounds__(256) void k_agg(const int* __restrict__ rowptr, const int* __restrict__ csr,
                                             const float* __restrict__ ss, const float* __restrict__ sd,
                                             const unsigned int* __restrict__ hb, const float* __restrict__ bias,
                                             float* __restrict__ z, int N) {
    __shared__ float2 ps[8 * CAP];
    const int tid = threadIdx.x;
    const int hw  = tid >> 5;          // half-wave 0..7 (node slot)
    const int p   = tid & 31;
    const int n   = blockIdx.x * 8 + hw;
    const bool valid = n < N;
    float2* myps = ps + hw * CAP;

    int ro = 0, deg = 0;
    float sdn = 0.f;
    if (valid) {
        ro  = rowptr[n];
        deg = rowptr[n + 1] - ro;
        sdn = sd[n];
    }

    if (deg <= CAP) {
        float sum = 0.f;
        for (int j = p; j < deg; j += 32) {
            int s = csr[ro + j];
            float e = ss[s] + sdn;
            e = fmaxf(e, NEG_SLOPE * e);
            float pe = __expf(e);
            myps[j] = make_float2(pe, __int_as_float(s));
            sum += pe;
        }
        sum = hred_sum(sum);
        float inv = 1.f / (sum + 1e-16f);

        float ax = 0.f, ay = 0.f, bx = 0.f, by = 0.f, cx = 0.f, cy = 0.f, dx = 0.f, dy = 0.f;
        int j = 0;
        for (; j + 3 < deg; j += 4) {
            float2 e0 = myps[j], e1 = myps[j + 1], e2 = myps[j + 2], e3 = myps[j + 3];
            unsigned int u0 = hb[(size_t)__float_as_int(e0.y) * 32 + p];
            unsigned int u1 = hb[(size_t)__float_as_int(e1.y) * 32 + p];
            unsigned int u2 = hb[(size_t)__float_as_int(e2.y) * 32 + p];
            unsigned int u3 = hb[(size_t)__float_as_int(e3.y) * 32 + p];
            ax = fmaf(bflo(u0), e0.x, ax); ay = fmaf(bfhi(u0), e0.x, ay);
            bx = fmaf(bflo(u1), e1.x, bx); by = fmaf(bfhi(u1), e1.x, by);
            cx = fmaf(bflo(u2), e2.x, cx); cy = fmaf(bfhi(u2), e2.x, cy);
            dx = fmaf(bflo(u3), e3.x, dx); dy = fmaf(bfhi(u3), e3.x, dy);
        }
        for (; j < deg; ++j) {
            float2 e0 = myps[j];
            unsigned int u0 = hb[(size_t)__float_as_int(e0.y) * 32 + p];
            ax = fmaf(bflo(u0), e0.x, ax); ay = fmaf(bfhi(u0), e0.x, ay);
        }
        float fx = (ax + bx) + (cx + dx);
        float fy = (ay + by) + (cy + dy);
        if (valid) {
            float2 ob = *(const float2*)&bias[p * 2];
            float ox = fmaf(fx, inv, ob.x);
            float oy = fmaf(fy, inv, ob.y);
            ox = (ox > 0.f) ? ox : __expf(ox) - 1.f;
            oy = (oy > 0.f) ? oy : __expf(oy) - 1.f;
            *(float2*)&z[(size_t)n * 64 + p * 2] = make_float2(ox, oy);
        }
    } else {
        float sum = 0.f;
        for (int j = p; j < deg; j += 32) {
            int s = csr[ro + j];
            float e = ss[s] + sdn;
            e = fmaxf(e, NEG_SLOPE * e);
            sum += __expf(e);
        }
        sum = hred_sum(sum);
        float inv = 1.f / (sum + 1e-16f);
        float fx = 0.f, fy = 0.f;
        for (int j = 0; j < deg; ++j) {
            int s = csr[ro + j];
            float e = ss[s] + sdn;
            e = fmaxf(e, NEG_SLOPE * e);
            float pe = __expf(e);
            unsigned int u = hb[(size_t)s * 32 + p];
            fx = fmaf(bflo(u), pe, fx); fy = fmaf(bfhi(u), pe, fy);
        }
        float2 ob = *(const float2*)&bias[p * 2];
        float ox = fmaf(fx, inv, ob.x);
        float oy = fmaf(fy, inv, ob.y);
        ox = (ox > 0.f) ? ox : __expf(ox) - 1.f;
        oy = (oy > 0.f) ? oy : __expf(oy) - 1.f;
        *(float2*)&z[(size_t)n * 64 + p * 2] = make_float2(ox, oy);
    }
}

// ---------------- launch ----------------

extern "C" void kernel_launch(void* const* d_in, const int* in_sizes, int n_in,
                              void* d_out, int out_size, void* d_ws, size_t ws_size,
                              hipStream_t stream) {
    const float* x   = (const float*)d_in[0];
    const int*   ei  = (const int*)d_in[1];
    const float* W0  = (const float*)d_in[2];
    const float* as0 = (const float*)d_in[3];
    const float* ad0 = (const float*)d_in[4];
    const float* b0  = (const float*)d_in[5];
    const float* W1  = (const float*)d_in[6];
    const float* as1 = (const float*)d_in[7];
    const float* ad1 = (const float*)d_in[8];
    const float* b1  = (const float*)d_in[9];
    const float* Wl  = (const float*)d_in[10];
    const float* bl  = (const float*)d_in[11];
    float* out = (float*)d_out;

    int N = in_sizes[0] / 128;
    int E = in_sizes[1] / 2;
    const int* srcp = ei;
    const int* dstp = ei + E;
    int nbuck = (N + BSZ - 1) >> BSH;

    char* wp = (char*)d_ws;
    auto alloc = [&](size_t bytes) { void* p = (void*)wp; wp += (bytes + 255) & ~(size_t)255; return p; };
    unsigned int* hb = (unsigned int*)alloc((size_t)N * 32 * 4);   // bf16-packed h
    float* z       = (float*)alloc((size_t)N * 64 * 4);
    float* ssb     = (float*)alloc((size_t)N * 4);
    float* sdb     = (float*)alloc((size_t)N * 4);
    int*   rowptr  = (int*)alloc((size_t)(N + 1) * 4);
    int*   csr     = (int*)alloc((size_t)(E + N) * 4);
    int*   ebuf    = (int*)alloc((size_t)E * 4);
    int*   bcount  = (int*)alloc(256 * 4);
    int*   eoff    = (int*)alloc(256 * 4);
    int*   boff    = (int*)alloc(256 * 4);
    int*   bcursor = (int*)alloc(256 * 4);

    // CSR build
    k_zero<<<1, 256, 0, stream>>>(bcount, 256);
    k_hist<<<256, 256, 0, stream>>>(dstp, bcount, E);
    k_bscan<<<1, 256, 0, stream>>>(bcount, eoff, boff, bcursor, rowptr, nbuck, N, E);
    k_scatter<<<(E + CHUNK - 1) / CHUNK, 256, 0, stream>>>(srcp, dstp, bcursor, ebuf, E);
    k_build<<<nbuck, 512, 0, stream>>>(eoff, boff, bcount, ebuf, rowptr, csr, N);

    int gb = (N + 127) / 128;
    // layer 0
    k_gemm<128, 64, true, true><<<gb, 256, 0, stream>>>(x, W0, as0, ad0, nullptr, hb, ssb, sdb, N);
    k_agg<<<(N + 7) / 8, 256, 0, stream>>>(rowptr, csr, ssb, sdb, hb, b0, z, N);
    // layer 1
    k_gemm<64, 64, true, true><<<gb, 256, 0, stream>>>(z, W1, as1, ad1, nullptr, hb, ssb, sdb, N);
    k_agg<<<(N + 7) / 8, 256, 0, stream>>>(rowptr, csr, ssb, sdb, hb, b1, z, N);
    // classifier
    k_gemm<64, 40, false, false><<<gb, 256, 0, stream>>>(z, Wl, nullptr, nullptr, bl, out, nullptr, nullptr, N);
}

// Round 7
// 280.479 us; speedup vs baseline: 1.2536x; 1.2536x over previous
//
#include <hip/hip_runtime.h>
#include <math.h>

#define NEG_SLOPE 0.2f
#define CAP 256     // max degree on the agg fast path
#define BSH 9       // node-bucket shift: 512 nodes/bucket
#define BSZ 512
#define CHUNK 8192  // edges per k_scatter block

typedef __attribute__((ext_vector_type(8))) short short8;   // 8 bf16 (4 VGPRs)
typedef __attribute__((ext_vector_type(4))) float f32x4;    // MFMA C/D

__device__ __forceinline__ float hred_sum(float v) {   // 32-wide (half-wave) reduce
#pragma unroll
    for (int o = 16; o >= 1; o >>= 1) v += __shfl_xor(v, o, 64);
    return v;
}
// fp32 -> bf16 (RNE), and bf16(lo/hi of uint) -> fp32
__device__ __forceinline__ unsigned int f2bf(float f) {
    unsigned int u = __float_as_uint(f);
    return (u + 0x7fffu + ((u >> 16) & 1u)) >> 16;
}
__device__ __forceinline__ float bflo(unsigned int u) { return __uint_as_float(u << 16); }
__device__ __forceinline__ float bfhi(unsigned int u) { return __uint_as_float(u & 0xffff0000u); }

// ---------------- CSR build: bucketed counting sort ----------------

__global__ __launch_bounds__(256) void k_zero(int* p, int n) {
    int i = blockIdx.x * 256 + threadIdx.x;
    if (i < n) p[i] = 0;
}

__global__ __launch_bounds__(256) void k_hist(const int* __restrict__ dst, int* __restrict__ bcount, int E) {
    __shared__ int lh[256];
    lh[threadIdx.x] = 0;
    __syncthreads();
    int stride = gridDim.x * 256;
    for (int i = blockIdx.x * 256 + threadIdx.x; i < E; i += stride)
        atomicAdd(&lh[dst[i] >> BSH], 1);
    __syncthreads();
    int c = lh[threadIdx.x];
    if (c) atomicAdd(&bcount[threadIdx.x], c);
}

__global__ __launch_bounds__(256) void k_bscan(const int* __restrict__ bcount,
                                               int* __restrict__ eoff, int* __restrict__ boff,
                                               int* __restrict__ bcursor, int* __restrict__ rowptr,
                                               int nbuck, int N, int E) {
    __shared__ int s1[256], s2[256];
    int t = threadIdx.x;
    int bc = (t < nbuck) ? bcount[t] : 0;
    int cn = 0;
    if (t < nbuck) { cn = N - (t << BSH); if (cn > BSZ) cn = BSZ; if (cn < 0) cn = 0; }
    int tot = bc + cn;
    s1[t] = bc; s2[t] = tot;
    __syncthreads();
#pragma unroll
    for (int off = 1; off < 256; off <<= 1) {
        int u1 = (t >= off) ? s1[t - off] : 0;
        int u2 = (t >= off) ? s2[t - off] : 0;
        __syncthreads();
        s1[t] += u1; s2[t] += u2;
        __syncthreads();
    }
    if (t < nbuck) {
        int e = s1[t] - bc, b = s2[t] - tot;
        eoff[t] = e; boff[t] = b; bcursor[t] = e;
    }
    if (t == 0) rowptr[N] = E + N;
}

__global__ __launch_bounds__(256) void k_scatter(const int* __restrict__ src, const int* __restrict__ dst,
                                                 int* __restrict__ bcursor, int* __restrict__ ebuf, int E) {
    __shared__ int lh[256], lb[256];
    int base = blockIdx.x * CHUNK;
    int end = base + CHUNK; if (end > E) end = E;
    lh[threadIdx.x] = 0;
    __syncthreads();
    for (int i = base + threadIdx.x; i < end; i += 256)
        atomicAdd(&lh[dst[i] >> BSH], 1);
    __syncthreads();
    int c = lh[threadIdx.x];
    lb[threadIdx.x] = c ? atomicAdd(&bcursor[threadIdx.x], c) : 0;
    lh[threadIdx.x] = 0;
    __syncthreads();
    for (int i = base + threadIdx.x; i < end; i += 256) {
        int d = dst[i], b = d >> BSH;
        int p = atomicAdd(&lh[b], 1);
        ebuf[lb[b] + p] = (src[i] << BSH) | (d & (BSZ - 1));
    }
}

__global__ __launch_bounds__(512) void k_build(const int* __restrict__ eoff, const int* __restrict__ boff,
                                               const int* __restrict__ bcount, const int* __restrict__ ebuf,
                                               int* __restrict__ rowptr, int* __restrict__ csr, int N) {
    __shared__ int sdeg[BSZ], sscan[BSZ];
    int b = blockIdx.x, t = threadIdx.x;
    int nlo = b << BSH;
    int cn = N - nlo; if (cn > BSZ) cn = BSZ;
    int e0 = eoff[b], ec = bcount[b], cb = boff[b];
    sdeg[t] = (t < cn) ? 1 : 0;
    __syncthreads();
    for (int i = t; i < ec; i += 512)
        atomicAdd(&sdeg[ebuf[e0 + i] & (BSZ - 1)], 1);
    __syncthreads();
    int v = sdeg[t];
    sscan[t] = v;
    __syncthreads();
#pragma unroll
    for (int off = 1; off < BSZ; off <<= 1) {
        int u = (t >= off) ? sscan[t - off] : 0;
        __syncthreads();
        sscan[t] += u;
        __syncthreads();
    }
    int excl = sscan[t] - v;
    if (t < cn) {
        rowptr[nlo + t] = cb + excl;
        csr[cb + excl] = nlo + t;
        sdeg[t] = excl + 1;
    }
    __syncthreads();
    for (int i = t; i < ec; i += 512) {
        int rec = ebuf[e0 + i];
        int p = atomicAdd(&sdeg[rec & (BSZ - 1)], 1);
        csr[cb + p] = rec >> BSH;
    }
}

// ---------------- GEMM via bf16 MFMA, split-precision A ----------------------
// H = X @ W (+bias). Block = 256 = 4 waves; each wave: 16 rows x OUTW cols.
// A = xh + xl (two bf16 terms, ~fp32 accuracy); W plain bf16 (error ~6e-4).
// W pre-packed in LDS as B-fragments (one barrier total). A-frags loaded
// directly from global (block's rows are L1-resident). MFMA 16x16x32:
//   A[m=lane&15][k=(lane>>4)*8+j], B[k][n=lane&15], C/D row=(lane>>4)*4+i.

template <int K, int OUTW, bool SS, bool HB>
__global__ __launch_bounds__(256) void k_gemm(const float* __restrict__ X,
                                              const float* __restrict__ W,
                                              const float* __restrict__ a_s,
                                              const float* __restrict__ a_d,
                                              const float* __restrict__ bias,
                                              void* __restrict__ Hout,
                                              float* __restrict__ ss,
                                              float* __restrict__ sd, int N) {
    constexpr int NKC = K / 32;               // k32 chunks
    constexpr int NC  = (OUTW + 15) / 16;     // 16-col tiles
    __shared__ __align__(16) short wfrag[NKC * NC * 64 * 8];
    __shared__ __align__(16) unsigned int hs[HB ? 4 : 1][16 * 32];  // per-wave epilogue

    const int tid  = threadIdx.x;
    const int lane = tid & 63;
    const int w    = tid >> 6;
    const int m    = lane & 15;     // A row / B col / C col
    const int q8   = lane >> 4;     // k-octet / C row-quad
    const int rowbase = blockIdx.x * 64 + w * 16;

    // stage W as pre-packed B-fragments (once)
    for (int f = tid; f < NKC * NC * 64; f += 256) {
        int flane = f & 63;
        int fc    = (f >> 6) % NC;
        int fkc   = (f >> 6) / NC;
        int col   = fc * 16 + (flane & 15);
        int k0    = fkc * 32 + (flane >> 4) * 8;
        short8 b;
#pragma unroll
        for (int j = 0; j < 8; ++j) {
            float v = (col < OUTW) ? W[(k0 + j) * OUTW + col] : 0.f;
            b[j] = (short)f2bf(v);
        }
        *(short8*)&wfrag[f * 8] = b;
    }
    __syncthreads();

    int grow = rowbase + m; if (grow >= N) grow = N - 1;
    const float* xrow = X + (size_t)grow * K + q8 * 8;

    f32x4 acc[NC];
#pragma unroll
    for (int c = 0; c < NC; ++c) acc[c] = (f32x4)0.f;

#pragma unroll
    for (int kc = 0; kc < NKC; ++kc) {
        float4 v0 = *(const float4*)(xrow + kc * 32);
        float4 v1 = *(const float4*)(xrow + kc * 32 + 4);
        float vv[8] = {v0.x, v0.y, v0.z, v0.w, v1.x, v1.y, v1.z, v1.w};
        short8 ah, al;
#pragma unroll
        for (int j = 0; j < 8; ++j) {
            unsigned int hb16 = f2bf(vv[j]);
            ah[j] = (short)hb16;
            al[j] = (short)f2bf(vv[j] - __uint_as_float(hb16 << 16));
        }
#pragma unroll
        for (int c = 0; c < NC; ++c) {
            short8 b = *(short8*)&wfrag[((kc * NC + c) * 64 + lane) * 8];
            acc[c] = __builtin_amdgcn_mfma_f32_16x16x32_bf16(ah, b, acc[c], 0, 0, 0);
            acc[c] = __builtin_amdgcn_mfma_f32_16x16x32_bf16(al, b, acc[c], 0, 0, 0);
        }
    }

    if (SS) {
        float asv[NC], adv[NC];
#pragma unroll
        for (int c = 0; c < NC; ++c) { asv[c] = a_s[c * 16 + m]; adv[c] = a_d[c * 16 + m]; }
#pragma unroll
        for (int i = 0; i < 4; ++i) {
            float s = 0.f, d = 0.f;
#pragma unroll
            for (int c = 0; c < NC; ++c) {
                s = fmaf(acc[c][i], asv[c], s);
                d = fmaf(acc[c][i], adv[c], d);
            }
#pragma unroll
            for (int o = 1; o <= 8; o <<= 1) {   // reduce the 16 col-lanes of this q8 group
                s += __shfl_xor(s, o, 64);
                d += __shfl_xor(d, o, 64);
            }
            int r = rowbase + q8 * 4 + i;
            if (m == 0 && r < N) { ss[r] = s; sd[r] = d; }
        }
    }

    if (HB) {
        // per-wave LDS transpose to bf16-packed rows (same-wave, no barrier needed)
        unsigned short* hsw = (unsigned short*)&hs[w][0];   // [16 rows][64 cols] bf16
#pragma unroll
        for (int c = 0; c < NC; ++c)
#pragma unroll
            for (int i = 0; i < 4; ++i)
                hsw[(q8 * 4 + i) * 64 + c * 16 + m] = (unsigned short)f2bf(acc[c][i]);
        unsigned int* hu = &hs[w][0];
        int row = lane >> 2, u0 = (lane & 3) * 8;
        uint4 va = *(uint4*)&hu[row * 32 + u0];
        uint4 vb = *(uint4*)&hu[row * 32 + u0 + 4];
        int r = rowbase + row;
        if (r < N) {
            unsigned int* hbp = (unsigned int*)Hout;
            *(uint4*)&hbp[(size_t)r * 32 + u0]     = va;
            *(uint4*)&hbp[(size_t)r * 32 + u0 + 4] = vb;
        }
    } else {
        float bv[NC];
#pragma unroll
        for (int c = 0; c < NC; ++c) {
            int col = c * 16 + m;
            bv[c] = (col < OUTW) ? bias[col] : 0.f;
        }
        float* O = (float*)Hout;
#pragma unroll
        for (int i = 0; i < 4; ++i) {
            int r = rowbase + q8 * 4 + i;
            if (r < N) {
#pragma unroll
                for (int c = 0; c < NC; ++c) {
                    int col = c * 16 + m;
                    if (col < OUTW) O[(size_t)r * OUTW + col] = acc[c][i] + bv[c];
                }
            }
        }
    }
}

// ---------------- Aggregation: z[n] = elu( sum_j alpha_j h[src_j] + b ) ------
// half-wave (32 lanes) per node, 8 nodes/block. Softmax without max-subtraction
// (scores bounded ~|10| << 88, shift-invariant). One fused score+exp+sum pass,
// then gather: lane p holds packed bf16 features 2p,2p+1 of the accumulator.

__global__ __launch_bounds__(256) void k_agg(const int* __restrict__ rowptr, const int* __restrict__ csr,
                                             const float* __restrict__ ss, const float* __restrict__ sd,
                                             const unsigned int* __restrict__ hb, const float* __restrict__ bias,
                                             float* __restrict__ z, int N) {
    __shared__ float2 ps[8 * CAP];
    const int tid = threadIdx.x;
    const int hw  = tid >> 5;          // half-wave 0..7 (node slot)
    const int p   = tid & 31;
    const int n   = blockIdx.x * 8 + hw;
    const bool valid = n < N;
    float2* myps = ps + hw * CAP;

    int ro = 0, deg = 0;
    float sdn = 0.f;
    if (valid) {
        ro  = rowptr[n];
        deg = rowptr[n + 1] - ro;
        sdn = sd[n];
    }

    if (deg <= CAP) {
        float sum = 0.f;
        for (int j = p; j < deg; j += 32) {
            int s = csr[ro + j];
            float e = ss[s] + sdn;
            e = fmaxf(e, NEG_SLOPE * e);
            float pe = __expf(e);
            myps[j] = make_float2(pe, __int_as_float(s));
            sum += pe;
        }
        sum = hred_sum(sum);
        float inv = 1.f / (sum + 1e-16f);

        float ax = 0.f, ay = 0.f, bx = 0.f, by = 0.f, cx = 0.f, cy = 0.f, dx = 0.f, dy = 0.f;
        int j = 0;
        for (; j + 3 < deg; j += 4) {
            float2 e0 = myps[j], e1 = myps[j + 1], e2 = myps[j + 2], e3 = myps[j + 3];
            unsigned int u0 = hb[(size_t)__float_as_int(e0.y) * 32 + p];
            unsigned int u1 = hb[(size_t)__float_as_int(e1.y) * 32 + p];
            unsigned int u2 = hb[(size_t)__float_as_int(e2.y) * 32 + p];
            unsigned int u3 = hb[(size_t)__float_as_int(e3.y) * 32 + p];
            ax = fmaf(bflo(u0), e0.x, ax); ay = fmaf(bfhi(u0), e0.x, ay);
            bx = fmaf(bflo(u1), e1.x, bx); by = fmaf(bfhi(u1), e1.x, by);
            cx = fmaf(bflo(u2), e2.x, cx); cy = fmaf(bfhi(u2), e2.x, cy);
            dx = fmaf(bflo(u3), e3.x, dx); dy = fmaf(bfhi(u3), e3.x, dy);
        }
        for (; j < deg; ++j) {
            float2 e0 = myps[j];
            unsigned int u0 = hb[(size_t)__float_as_int(e0.y) * 32 + p];
            ax = fmaf(bflo(u0), e0.x, ax); ay = fmaf(bfhi(u0), e0.x, ay);
        }
        float fx = (ax + bx) + (cx + dx);
        float fy = (ay + by) + (cy + dy);
        if (valid) {
            float2 ob = *(const float2*)&bias[p * 2];
            float ox = fmaf(fx, inv, ob.x);
            float oy = fmaf(fy, inv, ob.y);
            ox = (ox > 0.f) ? ox : __expf(ox) - 1.f;
            oy = (oy > 0.f) ? oy : __expf(oy) - 1.f;
            *(float2*)&z[(size_t)n * 64 + p * 2] = make_float2(ox, oy);
        }
    } else {
        float sum = 0.f;
        for (int j = p; j < deg; j += 32) {
            int s = csr[ro + j];
            float e = ss[s] + sdn;
            e = fmaxf(e, NEG_SLOPE * e);
            sum += __expf(e);
        }
        sum = hred_sum(sum);
        float inv = 1.f / (sum + 1e-16f);
        float fx = 0.f, fy = 0.f;
        for (int j = 0; j < deg; ++j) {
            int s = csr[ro + j];
            float e = ss[s] + sdn;
            e = fmaxf(e, NEG_SLOPE * e);
            float pe = __expf(e);
            unsigned int u = hb[(size_t)s * 32 + p];
            fx = fmaf(bflo(u), pe, fx); fy = fmaf(bfhi(u), pe, fy);
        }
        float2 ob = *(const float2*)&bias[p * 2];
        float ox = fmaf(fx, inv, ob.x);
        float oy = fmaf(fy, inv, ob.y);
        ox = (ox > 0.f) ? ox : __expf(ox) - 1.f;
        oy = (oy > 0.f) ? oy : __expf(oy) - 1.f;
        *(float2*)&z[(size_t)n * 64 + p * 2] = make_float2(ox, oy);
    }
}

// ---------------- launch ----------------

extern "C" void kernel_launch(void* const* d_in, const int* in_sizes, int n_in,
                              void* d_out, int out_size, void* d_ws, size_t ws_size,
                              hipStream_t stream) {
    const float* x   = (const float*)d_in[0];
    const int*   ei  = (const int*)d_in[1];
    const float* W0  = (const float*)d_in[2];
    const float* as0 = (const float*)d_in[3];
    const float* ad0 = (const float*)d_in[4];
    const float* b0  = (const float*)d_in[5];
    const float* W1  = (const float*)d_in[6];
    const float* as1 = (const float*)d_in[7];
    const float* ad1 = (const float*)d_in[8];
    const float* b1  = (const float*)d_in[9];
    const float* Wl  = (const float*)d_in[10];
    const float* bl  = (const float*)d_in[11];
    float* out = (float*)d_out;

    int N = in_sizes[0] / 128;
    int E = in_sizes[1] / 2;
    const int* srcp = ei;
    const int* dstp = ei + E;
    int nbuck = (N + BSZ - 1) >> BSH;

    char* wp = (char*)d_ws;
    auto alloc = [&](size_t bytes) { void* p = (void*)wp; wp += (bytes + 255) & ~(size_t)255; return p; };
    unsigned int* hb = (unsigned int*)alloc((size_t)N * 32 * 4);   // bf16-packed h
    float* z       = (float*)alloc((size_t)N * 64 * 4);
    float* ssb     = (float*)alloc((size_t)N * 4);
    float* sdb     = (float*)alloc((size_t)N * 4);
    int*   rowptr  = (int*)alloc((size_t)(N + 1) * 4);
    int*   csr     = (int*)alloc((size_t)(E + N) * 4);
    int*   ebuf    = (int*)alloc((size_t)E * 4);
    int*   bcount  = (int*)alloc(256 * 4);
    int*   eoff    = (int*)alloc(256 * 4);
    int*   boff    = (int*)alloc(256 * 4);
    int*   bcursor = (int*)alloc(256 * 4);

    // CSR build
    k_zero<<<1, 256, 0, stream>>>(bcount, 256);
    k_hist<<<256, 256, 0, stream>>>(dstp, bcount, E);
    k_bscan<<<1, 256, 0, stream>>>(bcount, eoff, boff, bcursor, rowptr, nbuck, N, E);
    k_scatter<<<(E + CHUNK - 1) / CHUNK, 256, 0, stream>>>(srcp, dstp, bcursor, ebuf, E);
    k_build<<<nbuck, 512, 0, stream>>>(eoff, boff, bcount, ebuf, rowptr, csr, N);

    int gb = (N + 63) / 64;
    // layer 0
    k_gemm<128, 64, true, true><<<gb, 256, 0, stream>>>(x, W0, as0, ad0, nullptr, hb, ssb, sdb, N);
    k_agg<<<(N + 7) / 8, 256, 0, stream>>>(rowptr, csr, ssb, sdb, hb, b0, z, N);
    // layer 1
    k_gemm<64, 64, true, true><<<gb, 256, 0, stream>>>(z, W1, as1, ad1, nullptr, hb, ssb, sdb, N);
    k_agg<<<(N + 7) / 8, 256, 0, stream>>>(rowptr, csr, ssb, sdb, hb, b1, z, N);
    // classifier
    k_gemm<64, 40, false, false><<<gb, 256, 0, stream>>>(z, Wl, nullptr, nullptr, bl, out, nullptr, nullptr, N);
}